// Round 6
// baseline (967.203 us; speedup 1.0000x reference)
//
#include <hip/hip_runtime.h>
#include <hip/hip_bf16.h>

typedef __attribute__((ext_vector_type(4))) float f32x4;
typedef _Float16 f16;
typedef __attribute__((ext_vector_type(8))) _Float16 f16x8;
typedef __attribute__((ext_vector_type(4))) _Float16 f16x4;
typedef __attribute__((ext_vector_type(2))) __fp16 pk16x2;   // cvt_pkrtz native return

#define S_LEN 2048
#define D_DIM 128
#define QBLK 128
#define KVBLK 64
#define NKV (S_LEN / KVBLK)

// softmax(x2 @ x3^T) @ x3 ; Q = x2, K = V = x3, no scale. fp16 MFMA path.
// 8 waves x 16 q-rows; K/V tile loaded once per block (4x4 fp32 per thread),
// written to Ksh + Vsh^T; T14 async-stage; T13 defer-max; packed cvt.
__global__ __launch_bounds__(512, 6) void attn_kernel(
    const float* __restrict__ Q, const float* __restrict__ KV,
    float* __restrict__ Out)
{
    // XCD-aware swizzle: 1024 blocks % 8 == 0 -> bijective chunked map.
    unsigned b = blockIdx.x;
    unsigned cpx = gridDim.x >> 3;               // 128
    unsigned work = (b & 7u) * cpx + (b >> 3);
    unsigned head = work >> 4;                   // 64 heads
    unsigned qt = work & 15u;                    // 16 q-tiles per head

    const float* Qh = Q + (size_t)head * (S_LEN * D_DIM) + (size_t)qt * QBLK * D_DIM;
    const float* Kh = KV + (size_t)head * (S_LEN * D_DIM);
    float* Oh = Out + (size_t)head * (S_LEN * D_DIM) + (size_t)qt * QBLK * D_DIM;

    const int tid = threadIdx.x;
    const int wv = tid >> 6;        // 0..7
    const int lane = tid & 63;
    const int lo = lane & 15;
    const int hi = lane >> 4;

    // 16 + 16 + 16 = 48 KB -> 3 blocks/CU (144 KB of 160 KB LDS).
    __shared__ __align__(16) f16 Ksh[KVBLK * D_DIM];     // [kv][d], swizzled
    __shared__ __align__(16) f16 Vsh[D_DIM * KVBLK];     // [d][kv] transposed, swizzled
    __shared__ __align__(16) f16 Psh[8][16 * KVBLK];     // per-wave [q][kv], swizzled

    // staging map: thread owns 4x4 fp32 block rows sg*4.., cols sc*4..
    const int sg = tid >> 5;        // 0..15
    const int sc = tid & 31;        // 0..31

    // ---- Q fragments: Q[wv*16+lo][kc*32 + hi*8 + j] as fp16 (pkrtz) ----
    f16x8 qf[4];
    {
        const float* qr = Qh + (wv * 16 + lo) * D_DIM + hi * 8;
        #pragma unroll
        for (int kc = 0; kc < 4; ++kc) {
            f32x4 a = *(const f32x4*)(qr + kc * 32);
            f32x4 c = *(const f32x4*)(qr + kc * 32 + 4);
            pk16x2 p0 = __builtin_amdgcn_cvt_pkrtz(a[0], a[1]);
            pk16x2 p1 = __builtin_amdgcn_cvt_pkrtz(a[2], a[3]);
            pk16x2 p2 = __builtin_amdgcn_cvt_pkrtz(c[0], c[1]);
            pk16x2 p3 = __builtin_amdgcn_cvt_pkrtz(c[2], c[3]);
            f16x8 q;
            q[0] = (f16)p0[0]; q[1] = (f16)p0[1]; q[2] = (f16)p1[0]; q[3] = (f16)p1[1];
            q[4] = (f16)p2[0]; q[5] = (f16)p2[1]; q[6] = (f16)p3[0]; q[7] = (f16)p3[1];
            qf[kc] = q;
        }
    }

    f32x4 oacc[8];
    #pragma unroll
    for (int n = 0; n < 8; ++n) oacc[n] = (f32x4){0.f, 0.f, 0.f, 0.f};
    float m_run = -1e30f, l_run = 0.f;

    f32x4 stg[4];

    #define STAGE_LOAD(KT) do {                                               \
        const float* p_ = Kh + (size_t)(KT) * KVBLK * D_DIM + sg * 4 * D_DIM + sc * 4; \
        stg[0] = *(const f32x4*)(p_);                                         \
        stg[1] = *(const f32x4*)(p_ + D_DIM);                                 \
        stg[2] = *(const f32x4*)(p_ + 2 * D_DIM);                             \
        stg[3] = *(const f32x4*)(p_ + 3 * D_DIM);                             \
    } while (0)

    #define STAGE_WRITE() do {                                                \
        _Pragma("unroll")                                                     \
        for (int i_ = 0; i_ < 4; ++i_) {                                      \
            int row_ = sg * 4 + i_;                                           \
            int fK_ = (row_ & 7) ^ ((row_ >> 3) & 7);                         \
            pk16x2 a_ = __builtin_amdgcn_cvt_pkrtz(stg[i_][0], stg[i_][1]);   \
            pk16x2 b_ = __builtin_amdgcn_cvt_pkrtz(stg[i_][2], stg[i_][3]);   \
            f16x4 w_;                                                         \
            w_[0] = (f16)a_[0]; w_[1] = (f16)a_[1];                           \
            w_[2] = (f16)b_[0]; w_[3] = (f16)b_[1];                           \
            *(f16x4*)&Ksh[row_ * D_DIM + ((sc * 4) ^ (fK_ << 3))] = w_;       \
        }                                                                     \
        _Pragma("unroll")                                                     \
        for (int j_ = 0; j_ < 4; ++j_) {                                      \
            int d_ = sc * 4 + j_;                                             \
            int g_ = (d_ & 7) ^ ((d_ >> 3) & 7);                              \
            pk16x2 a_ = __builtin_amdgcn_cvt_pkrtz(stg[0][j_], stg[1][j_]);   \
            pk16x2 b_ = __builtin_amdgcn_cvt_pkrtz(stg[2][j_], stg[3][j_]);   \
            f16x4 w_;                                                         \
            w_[0] = (f16)a_[0]; w_[1] = (f16)a_[1];                           \
            w_[2] = (f16)b_[0]; w_[3] = (f16)b_[1];                           \
            *(f16x4*)&Vsh[d_ * KVBLK + ((sg * 4) ^ (g_ << 3))] = w_;          \
        }                                                                     \
    } while (0)

    // prologue: tile 0
    STAGE_LOAD(0);
    STAGE_WRITE();
    __syncthreads();

    for (int kt = 0; kt < NKV; ++kt) {
        // issue next tile's global loads early; consumed after the barrier
        if (kt + 1 < NKV) STAGE_LOAD(kt + 1);

        // ---- swapped QK^T: S^T = K_tile @ Q_wave^T ----
        f32x4 st[4];
        #pragma unroll
        for (int m = 0; m < 4; ++m) st[m] = (f32x4){0.f, 0.f, 0.f, 0.f};
        __builtin_amdgcn_s_setprio(1);
        #pragma unroll
        for (int m = 0; m < 4; ++m) {
            int row = m * 16 + lo;
            int fK = (row & 7) ^ ((row >> 3) & 7);
            #pragma unroll
            for (int kc = 0; kc < 4; ++kc) {
                f16x8 kf = *(const f16x8*)&Ksh[row * D_DIM + ((kc * 32 + hi * 8) ^ (fK << 3))];
                st[m] = __builtin_amdgcn_mfma_f32_16x16x32_f16(kf, qf[kc], st[m], 0, 0, 0);
            }
        }
        __builtin_amdgcn_s_setprio(0);
        // lane holds S^T[kv = m*16 + hi*4 + r][q = wv*16 + lo]

        // ---- online softmax with T13 defer-max (THR=8) ----
        float tmax = -1e30f;
        #pragma unroll
        for (int m = 0; m < 4; ++m)
            #pragma unroll
            for (int r = 0; r < 4; ++r) tmax = fmaxf(tmax, st[m][r]);
        tmax = fmaxf(tmax, __shfl_xor(tmax, 16, 64));
        tmax = fmaxf(tmax, __shfl_xor(tmax, 32, 64));

        bool skip = __all(tmax - m_run <= 8.0f);
        float mnew = skip ? m_run : fmaxf(m_run, tmax);

        float ls = 0.f;
        #pragma unroll
        for (int m = 0; m < 4; ++m) {
            #pragma unroll
            for (int r = 0; r < 4; ++r) {
                float p = __expf(st[m][r] - mnew);
                st[m][r] = p;
                ls += p;
            }
        }
        ls += __shfl_xor(ls, 16, 64);
        ls += __shfl_xor(ls, 32, 64);

        if (!skip) {
            float scale = __expf(m_run - mnew);
            l_run = l_run * scale + ls;
            float sc4[4];
            #pragma unroll
            for (int r = 0; r < 4; ++r) sc4[r] = __shfl(scale, hi * 4 + r, 64);
            #pragma unroll
            for (int n = 0; n < 8; ++n)
                #pragma unroll
                for (int r = 0; r < 4; ++r) oacc[n][r] *= sc4[r];
            m_run = mnew;
        } else {
            l_run += ls;
        }

        // ---- P -> LDS (fp16), per-wave buffer, no cross-wave hazard ----
        const int swp = (lo & 7) << 3;
        #pragma unroll
        for (int m = 0; m < 4; ++m) {
            pk16x2 a2 = __builtin_amdgcn_cvt_pkrtz(st[m][0], st[m][1]);
            pk16x2 b2 = __builtin_amdgcn_cvt_pkrtz(st[m][2], st[m][3]);
            f16x4 w;
            w[0] = (f16)a2[0]; w[1] = (f16)a2[1]; w[2] = (f16)b2[0]; w[3] = (f16)b2[1];
            int col = (m * 16 + hi * 4) ^ swp;
            *(f16x4*)&Psh[wv][lo * KVBLK + col] = w;
        }

        // ---- PV: O += P @ V ----
        __builtin_amdgcn_s_setprio(1);
        #pragma unroll
        for (int kc2 = 0; kc2 < 2; ++kc2) {
            f16x8 pf = *(const f16x8*)&Psh[wv][lo * KVBLK + ((kc2 * 32 + hi * 8) ^ swp)];
            #pragma unroll
            for (int n = 0; n < 8; ++n) {
                int d = n * 16 + lo;
                int g = (d & 7) ^ ((d >> 3) & 7);
                f16x8 vf = *(const f16x8*)&Vsh[d * KVBLK + ((kc2 * 32 + hi * 8) ^ (g << 3))];
                oacc[n] = __builtin_amdgcn_mfma_f32_16x16x32_f16(pf, vf, oacc[n], 0, 0, 0);
            }
        }
        __builtin_amdgcn_s_setprio(0);

        __syncthreads();                    // all waves done reading Ksh/Vsh
        if (kt + 1 < NKV) {
            STAGE_WRITE();                  // overwrite with next tile
            __syncthreads();                // next tile visible to all
        }
    }

    // ---- epilogue: O / l, write fp32 ----
    float inv = 1.0f / l_run;   // valid at lane's q = lo
    float rl[4];
    #pragma unroll
    for (int r = 0; r < 4; ++r) rl[r] = __shfl(inv, hi * 4 + r, 64);
    #pragma unroll
    for (int n = 0; n < 8; ++n)
        #pragma unroll
        for (int r = 0; r < 4; ++r)
            Oh[(wv * 16 + hi * 4 + r) * D_DIM + n * 16 + lo] = oacc[n][r] * rl[r];
}

extern "C" void kernel_launch(void* const* d_in, const int* in_sizes, int n_in,
                              void* d_out, int out_size, void* d_ws, size_t ws_size,
                              hipStream_t stream) {
    const float* x2 = (const float*)d_in[0];
    const float* x3 = (const float*)d_in[1];
    float* out = (float*)d_out;
    dim3 grid(1024), block(512);
    hipLaunchKernelGGL(attn_kernel, grid, block, 0, stream, x2, x3, out);
}

// Round 7
// 410.831 us; speedup vs baseline: 2.3543x; 2.3543x over previous
//
#include <hip/hip_runtime.h>
#include <hip/hip_bf16.h>

typedef __attribute__((ext_vector_type(4))) float f32x4;
typedef _Float16 f16;
typedef __attribute__((ext_vector_type(8))) _Float16 f16x8;
typedef __attribute__((ext_vector_type(4))) _Float16 f16x4;
typedef __attribute__((ext_vector_type(2))) __fp16 pk16x2;   // cvt_pkrtz native return

#define S_LEN 2048
#define D_DIM 128
#define QBLK 128
#define KVBLK 64
#define NKV (S_LEN / KVBLK)

// softmax(x2 @ x3^T) @ x3 ; Q = x2, K = V = x3, no scale. fp16 MFMA path.
// 8 waves x 16 q-rows; K/V tile loaded once per block (4x4 fp32 per thread);
// K/V double-buffered in LDS -> ONE barrier per tile; T14 async-stage;
// T13 defer-max; packed cvt. launch_bounds(512,4): VGPR=64, no spill
// (512,6 in round 6 forced VGPR=40 -> scratch spill -> 1.65 GB fetch).
__global__ __launch_bounds__(512, 4) void attn_kernel(
    const float* __restrict__ Q, const float* __restrict__ KV,
    float* __restrict__ Out)
{
    // XCD-aware swizzle: 1024 blocks % 8 == 0 -> bijective chunked map.
    unsigned b = blockIdx.x;
    unsigned cpx = gridDim.x >> 3;               // 128
    unsigned work = (b & 7u) * cpx + (b >> 3);
    unsigned head = work >> 4;                   // 64 heads
    unsigned qt = work & 15u;                    // 16 q-tiles per head

    const float* Qh = Q + (size_t)head * (S_LEN * D_DIM) + (size_t)qt * QBLK * D_DIM;
    const float* Kh = KV + (size_t)head * (S_LEN * D_DIM);
    float* Oh = Out + (size_t)head * (S_LEN * D_DIM) + (size_t)qt * QBLK * D_DIM;

    const int tid = threadIdx.x;
    const int wv = tid >> 6;        // 0..7
    const int lane = tid & 63;
    const int lo = lane & 15;
    const int hi = lane >> 4;

    // 2*16 + 2*16 + 16 = 80 KB -> 2 blocks/CU (steady; grid = 2 clean passes).
    __shared__ __align__(16) f16 Ksh[2][KVBLK * D_DIM];   // [buf][kv][d], swizzled
    __shared__ __align__(16) f16 Vsh[2][D_DIM * KVBLK];   // [buf][d][kv] transposed, swizzled
    __shared__ __align__(16) f16 Psh[8][16 * KVBLK];      // per-wave [q][kv], swizzled

    // staging map: thread owns 4x4 fp32 block rows sg*4.., cols sc*4..
    const int sg = tid >> 5;        // 0..15
    const int sc = tid & 31;        // 0..31

    // ---- Q fragments: Q[wv*16+lo][kc*32 + hi*8 + j] as fp16 (pkrtz) ----
    f16x8 qf[4];
    {
        const float* qr = Qh + (wv * 16 + lo) * D_DIM + hi * 8;
        #pragma unroll
        for (int kc = 0; kc < 4; ++kc) {
            f32x4 a = *(const f32x4*)(qr + kc * 32);
            f32x4 c = *(const f32x4*)(qr + kc * 32 + 4);
            pk16x2 p0 = __builtin_amdgcn_cvt_pkrtz(a[0], a[1]);
            pk16x2 p1 = __builtin_amdgcn_cvt_pkrtz(a[2], a[3]);
            pk16x2 p2 = __builtin_amdgcn_cvt_pkrtz(c[0], c[1]);
            pk16x2 p3 = __builtin_amdgcn_cvt_pkrtz(c[2], c[3]);
            f16x8 q;
            q[0] = (f16)p0[0]; q[1] = (f16)p0[1]; q[2] = (f16)p1[0]; q[3] = (f16)p1[1];
            q[4] = (f16)p2[0]; q[5] = (f16)p2[1]; q[6] = (f16)p3[0]; q[7] = (f16)p3[1];
            qf[kc] = q;
        }
    }

    f32x4 oacc[8];
    #pragma unroll
    for (int n = 0; n < 8; ++n) oacc[n] = (f32x4){0.f, 0.f, 0.f, 0.f};
    float m_run = -1e30f, l_run = 0.f;

    f32x4 stg[4];

    #define STAGE_LOAD(KT) do {                                               \
        const float* p_ = Kh + (size_t)(KT) * KVBLK * D_DIM + sg * 4 * D_DIM + sc * 4; \
        stg[0] = *(const f32x4*)(p_);                                         \
        stg[1] = *(const f32x4*)(p_ + D_DIM);                                 \
        stg[2] = *(const f32x4*)(p_ + 2 * D_DIM);                             \
        stg[3] = *(const f32x4*)(p_ + 3 * D_DIM);                             \
    } while (0)

    #define STAGE_WRITE(BUF) do {                                             \
        _Pragma("unroll")                                                     \
        for (int i_ = 0; i_ < 4; ++i_) {                                      \
            int row_ = sg * 4 + i_;                                           \
            int fK_ = (row_ & 7) ^ ((row_ >> 3) & 7);                         \
            pk16x2 a_ = __builtin_amdgcn_cvt_pkrtz(stg[i_][0], stg[i_][1]);   \
            pk16x2 b_ = __builtin_amdgcn_cvt_pkrtz(stg[i_][2], stg[i_][3]);   \
            f16x4 w_;                                                         \
            w_[0] = (f16)a_[0]; w_[1] = (f16)a_[1];                           \
            w_[2] = (f16)b_[0]; w_[3] = (f16)b_[1];                           \
            *(f16x4*)&Ksh[BUF][row_ * D_DIM + ((sc * 4) ^ (fK_ << 3))] = w_;  \
        }                                                                     \
        _Pragma("unroll")                                                     \
        for (int j_ = 0; j_ < 4; ++j_) {                                      \
            int d_ = sc * 4 + j_;                                             \
            int g_ = (d_ & 7) ^ ((d_ >> 3) & 7);                              \
            pk16x2 a_ = __builtin_amdgcn_cvt_pkrtz(stg[0][j_], stg[1][j_]);   \
            pk16x2 b_ = __builtin_amdgcn_cvt_pkrtz(stg[2][j_], stg[3][j_]);   \
            f16x4 w_;                                                         \
            w_[0] = (f16)a_[0]; w_[1] = (f16)a_[1];                           \
            w_[2] = (f16)b_[0]; w_[3] = (f16)b_[1];                           \
            *(f16x4*)&Vsh[BUF][d_ * KVBLK + ((sg * 4) ^ (g_ << 3))] = w_;     \
        }                                                                     \
    } while (0)

    // prologue: tile 0 into buf 0
    STAGE_LOAD(0);
    STAGE_WRITE(0);
    __syncthreads();

    for (int kt = 0; kt < NKV; ++kt) {
        const int cur = kt & 1;
        // issue next tile's global loads early; written to buf cur^1 at bottom
        if (kt + 1 < NKV) STAGE_LOAD(kt + 1);

        // ---- swapped QK^T: S^T = K_tile @ Q_wave^T ----
        f32x4 st[4];
        #pragma unroll
        for (int m = 0; m < 4; ++m) st[m] = (f32x4){0.f, 0.f, 0.f, 0.f};
        __builtin_amdgcn_s_setprio(1);
        #pragma unroll
        for (int m = 0; m < 4; ++m) {
            int row = m * 16 + lo;
            int fK = (row & 7) ^ ((row >> 3) & 7);
            #pragma unroll
            for (int kc = 0; kc < 4; ++kc) {
                f16x8 kf = *(const f16x8*)&Ksh[cur][row * D_DIM + ((kc * 32 + hi * 8) ^ (fK << 3))];
                st[m] = __builtin_amdgcn_mfma_f32_16x16x32_f16(kf, qf[kc], st[m], 0, 0, 0);
            }
        }
        __builtin_amdgcn_s_setprio(0);
        // lane holds S^T[kv = m*16 + hi*4 + r][q = wv*16 + lo]

        // ---- online softmax with T13 defer-max (THR=8) ----
        float tmax = -1e30f;
        #pragma unroll
        for (int m = 0; m < 4; ++m)
            #pragma unroll
            for (int r = 0; r < 4; ++r) tmax = fmaxf(tmax, st[m][r]);
        tmax = fmaxf(tmax, __shfl_xor(tmax, 16, 64));
        tmax = fmaxf(tmax, __shfl_xor(tmax, 32, 64));

        bool skip = __all(tmax - m_run <= 8.0f);
        float mnew = skip ? m_run : fmaxf(m_run, tmax);

        float ls = 0.f;
        #pragma unroll
        for (int m = 0; m < 4; ++m) {
            #pragma unroll
            for (int r = 0; r < 4; ++r) {
                float p = __expf(st[m][r] - mnew);
                st[m][r] = p;
                ls += p;
            }
        }
        ls += __shfl_xor(ls, 16, 64);
        ls += __shfl_xor(ls, 32, 64);

        if (!skip) {
            float scale = __expf(m_run - mnew);
            l_run = l_run * scale + ls;
            float sc4[4];
            #pragma unroll
            for (int r = 0; r < 4; ++r) sc4[r] = __shfl(scale, hi * 4 + r, 64);
            #pragma unroll
            for (int n = 0; n < 8; ++n)
                #pragma unroll
                for (int r = 0; r < 4; ++r) oacc[n][r] *= sc4[r];
            m_run = mnew;
        } else {
            l_run += ls;
        }

        // ---- P -> LDS (fp16), per-wave buffer, no cross-wave hazard ----
        const int swp = (lo & 7) << 3;
        #pragma unroll
        for (int m = 0; m < 4; ++m) {
            pk16x2 a2 = __builtin_amdgcn_cvt_pkrtz(st[m][0], st[m][1]);
            pk16x2 b2 = __builtin_amdgcn_cvt_pkrtz(st[m][2], st[m][3]);
            f16x4 w;
            w[0] = (f16)a2[0]; w[1] = (f16)a2[1]; w[2] = (f16)b2[0]; w[3] = (f16)b2[1];
            int col = (m * 16 + hi * 4) ^ swp;
            *(f16x4*)&Psh[wv][lo * KVBLK + col] = w;
        }

        // ---- PV: O += P @ V ----
        __builtin_amdgcn_s_setprio(1);
        #pragma unroll
        for (int kc2 = 0; kc2 < 2; ++kc2) {
            f16x8 pf = *(const f16x8*)&Psh[wv][lo * KVBLK + ((kc2 * 32 + hi * 8) ^ swp)];
            #pragma unroll
            for (int n = 0; n < 8; ++n) {
                int d = n * 16 + lo;
                int g = (d & 7) ^ ((d >> 3) & 7);
                f16x8 vf = *(const f16x8*)&Vsh[cur][d * KVBLK + ((kc2 * 32 + hi * 8) ^ (g << 3))];
                oacc[n] = __builtin_amdgcn_mfma_f32_16x16x32_f16(pf, vf, oacc[n], 0, 0, 0);
            }
        }
        __builtin_amdgcn_s_setprio(0);

        // ---- write next tile into the other buffer; ONE barrier per tile ----
        if (kt + 1 < NKV) STAGE_WRITE(cur ^ 1);
        __syncthreads();
    }

    // ---- epilogue: O / l, write fp32 ----
    float inv = 1.0f / l_run;   // valid at lane's q = lo
    float rl[4];
    #pragma unroll
    for (int r = 0; r < 4; ++r) rl[r] = __shfl(inv, hi * 4 + r, 64);
    #pragma unroll
    for (int n = 0; n < 8; ++n)
        #pragma unroll
        for (int r = 0; r < 4; ++r)
            Oh[(wv * 16 + hi * 4 + r) * D_DIM + n * 16 + lo] = oacc[n][r] * rl[r];
}

extern "C" void kernel_launch(void* const* d_in, const int* in_sizes, int n_in,
                              void* d_out, int out_size, void* d_ws, size_t ws_size,
                              hipStream_t stream) {
    const float* x2 = (const float*)d_in[0];
    const float* x3 = (const float*)d_in[1];
    float* out = (float*)d_out;
    dim3 grid(1024), block(512);
    hipLaunchKernelGGL(attn_kernel, grid, block, 0, stream, x2, x3, out);
}

// Round 8
// 175.322 us; speedup vs baseline: 5.5167x; 2.3433x over previous
//
#include <hip/hip_runtime.h>
#include <hip/hip_bf16.h>

typedef __attribute__((ext_vector_type(4))) float f32x4;
typedef _Float16 f16;
typedef __attribute__((ext_vector_type(8))) _Float16 f16x8;
typedef __attribute__((ext_vector_type(4))) _Float16 f16x4;
typedef __attribute__((ext_vector_type(2))) __fp16 pk16x2;   // cvt_pkrtz native return

#define S_LEN 2048
#define D_DIM 128
#define QBLK 128
#define KVBLK 64
#define NKV (S_LEN / KVBLK)

// softmax(x2 @ x3^T) @ x3 ; Q = x2, K = V = x3, no scale. fp16 MFMA path.
// 4 waves x 32 q-rows (2 x 16-q subtiles per wave): every K/V LDS read feeds
// TWO MFMAs -> LDS bytes/FLOP halved vs round 4 (which was LDS-pipe bound).
// Round-4 schedule: single K/V buffer, STAGE_LOAD at top, 2 barriers/tile.
__global__ __launch_bounds__(256, 2) void attn_kernel(
    const float* __restrict__ Q, const float* __restrict__ KV,
    float* __restrict__ Out)
{
    // XCD-aware swizzle: 1024 blocks % 8 == 0 -> bijective chunked map.
    unsigned b = blockIdx.x;
    unsigned cpx = gridDim.x >> 3;               // 128
    unsigned work = (b & 7u) * cpx + (b >> 3);
    unsigned head = work >> 4;                   // 64 heads
    unsigned qt = work & 15u;                    // 16 q-tiles per head

    const float* Qh = Q + (size_t)head * (S_LEN * D_DIM) + (size_t)qt * QBLK * D_DIM;
    const float* Kh = KV + (size_t)head * (S_LEN * D_DIM);
    float* Oh = Out + (size_t)head * (S_LEN * D_DIM) + (size_t)qt * QBLK * D_DIM;

    const int tid = threadIdx.x;
    const int wv = tid >> 6;        // 0..3
    const int lane = tid & 63;
    const int lo = lane & 15;
    const int hi = lane >> 4;

    // 16 + 16 + 16 = 48 KB
    __shared__ __align__(16) f16 Ksh[KVBLK * D_DIM];      // [kv][d], swizzled
    __shared__ __align__(16) f16 Vsh[D_DIM * KVBLK];      // [d][kv] transposed, swizzled
    __shared__ __align__(16) f16 Psh[4][2][16 * KVBLK];   // per-wave, per-qsub [q][kv]

    // staging map: thread owns 8 rows x 4 cols (rows srow.., cols scol..)
    const int srow = (tid >> 5) * 8;   // 0,8,..56
    const int scol = (tid & 31) * 4;   // 0,4,..124

    // ---- Q fragments for 2 q-subtiles: Q[wv*32 + t*16 + lo][kc*32 + hi*8 + j] ----
    f16x8 qf[2][4];
    #pragma unroll
    for (int t = 0; t < 2; ++t) {
        const float* qr = Qh + (wv * 32 + t * 16 + lo) * D_DIM + hi * 8;
        #pragma unroll
        for (int kc = 0; kc < 4; ++kc) {
            f32x4 a = *(const f32x4*)(qr + kc * 32);
            f32x4 c = *(const f32x4*)(qr + kc * 32 + 4);
            pk16x2 p0 = __builtin_amdgcn_cvt_pkrtz(a[0], a[1]);
            pk16x2 p1 = __builtin_amdgcn_cvt_pkrtz(a[2], a[3]);
            pk16x2 p2 = __builtin_amdgcn_cvt_pkrtz(c[0], c[1]);
            pk16x2 p3 = __builtin_amdgcn_cvt_pkrtz(c[2], c[3]);
            f16x8 q;
            q[0] = (f16)p0[0]; q[1] = (f16)p0[1]; q[2] = (f16)p1[0]; q[3] = (f16)p1[1];
            q[4] = (f16)p2[0]; q[5] = (f16)p2[1]; q[6] = (f16)p3[0]; q[7] = (f16)p3[1];
            qf[t][kc] = q;
        }
    }

    f32x4 oacc[2][8];
    #pragma unroll
    for (int t = 0; t < 2; ++t)
        #pragma unroll
        for (int n = 0; n < 8; ++n) oacc[t][n] = (f32x4){0.f, 0.f, 0.f, 0.f};
    float mr[2] = {-1e30f, -1e30f};
    float lr[2] = {0.f, 0.f};

    f32x4 stg[8];

    #define STAGE_LOAD(KT) do {                                               \
        const float* p_ = Kh + (size_t)(KT) * KVBLK * D_DIM + srow * D_DIM + scol; \
        _Pragma("unroll")                                                     \
        for (int i_ = 0; i_ < 8; ++i_) stg[i_] = *(const f32x4*)(p_ + i_ * D_DIM); \
    } while (0)

    #define STAGE_WRITE() do {                                                \
        _Pragma("unroll")                                                     \
        for (int i_ = 0; i_ < 8; ++i_) {                                      \
            int row_ = srow + i_;                                             \
            int fK_ = (row_ & 7) ^ ((row_ >> 3) & 7);                         \
            pk16x2 a_ = __builtin_amdgcn_cvt_pkrtz(stg[i_][0], stg[i_][1]);   \
            pk16x2 b_ = __builtin_amdgcn_cvt_pkrtz(stg[i_][2], stg[i_][3]);   \
            f16x4 w_;                                                         \
            w_[0] = (f16)a_[0]; w_[1] = (f16)a_[1];                           \
            w_[2] = (f16)b_[0]; w_[3] = (f16)b_[1];                           \
            *(f16x4*)&Ksh[row_ * D_DIM + (scol ^ (fK_ << 3))] = w_;           \
        }                                                                     \
        _Pragma("unroll")                                                     \
        for (int j_ = 0; j_ < 4; ++j_) {                                      \
            int d_ = scol + j_;                                               \
            int g_ = (d_ & 7) ^ ((d_ >> 3) & 7);                              \
            pk16x2 a0_ = __builtin_amdgcn_cvt_pkrtz(stg[0][j_], stg[1][j_]);  \
            pk16x2 a1_ = __builtin_amdgcn_cvt_pkrtz(stg[2][j_], stg[3][j_]);  \
            pk16x2 a2_ = __builtin_amdgcn_cvt_pkrtz(stg[4][j_], stg[5][j_]);  \
            pk16x2 a3_ = __builtin_amdgcn_cvt_pkrtz(stg[6][j_], stg[7][j_]);  \
            f16x8 w_;                                                         \
            w_[0] = (f16)a0_[0]; w_[1] = (f16)a0_[1];                         \
            w_[2] = (f16)a1_[0]; w_[3] = (f16)a1_[1];                         \
            w_[4] = (f16)a2_[0]; w_[5] = (f16)a2_[1];                         \
            w_[6] = (f16)a3_[0]; w_[7] = (f16)a3_[1];                         \
            *(f16x8*)&Vsh[d_ * KVBLK + (srow ^ (g_ << 3))] = w_;              \
        }                                                                     \
    } while (0)

    // prologue: tile 0
    STAGE_LOAD(0);
    STAGE_WRITE();
    __syncthreads();

    for (int kt = 0; kt < NKV; ++kt) {
        // issue next tile's global loads early; consumed after the barrier
        if (kt + 1 < NKV) STAGE_LOAD(kt + 1);

        // ---- swapped QK^T: S^T = K_tile @ Q^T, one kf read -> 2 MFMAs ----
        f32x4 st[2][4];
        #pragma unroll
        for (int t = 0; t < 2; ++t)
            #pragma unroll
            for (int m = 0; m < 4; ++m) st[t][m] = (f32x4){0.f, 0.f, 0.f, 0.f};
        __builtin_amdgcn_s_setprio(1);
        #pragma unroll
        for (int m = 0; m < 4; ++m) {
            int row = m * 16 + lo;
            int fK = (row & 7) ^ ((row >> 3) & 7);
            #pragma unroll
            for (int kc = 0; kc < 4; ++kc) {
                f16x8 kf = *(const f16x8*)&Ksh[row * D_DIM + ((kc * 32 + hi * 8) ^ (fK << 3))];
                st[0][m] = __builtin_amdgcn_mfma_f32_16x16x32_f16(kf, qf[0][kc], st[0][m], 0, 0, 0);
                st[1][m] = __builtin_amdgcn_mfma_f32_16x16x32_f16(kf, qf[1][kc], st[1][m], 0, 0, 0);
            }
        }
        __builtin_amdgcn_s_setprio(0);
        // lane holds S^T[kv = m*16 + hi*4 + r][q = wv*32 + t*16 + lo]

        // ---- online softmax per q-subtile, T13 defer-max (THR=8) ----
        const int swp = (lo & 7) << 3;
        #pragma unroll
        for (int t = 0; t < 2; ++t) {
            float tmax = -1e30f;
            #pragma unroll
            for (int m = 0; m < 4; ++m)
                #pragma unroll
                for (int r = 0; r < 4; ++r) tmax = fmaxf(tmax, st[t][m][r]);
            tmax = fmaxf(tmax, __shfl_xor(tmax, 16, 64));
            tmax = fmaxf(tmax, __shfl_xor(tmax, 32, 64));

            bool skip = __all(tmax - mr[t] <= 8.0f);
            float mnew = skip ? mr[t] : fmaxf(mr[t], tmax);

            float ls = 0.f;
            #pragma unroll
            for (int m = 0; m < 4; ++m) {
                #pragma unroll
                for (int r = 0; r < 4; ++r) {
                    float p = __expf(st[t][m][r] - mnew);
                    st[t][m][r] = p;
                    ls += p;
                }
            }
            ls += __shfl_xor(ls, 16, 64);
            ls += __shfl_xor(ls, 32, 64);

            if (!skip) {
                float scale = __expf(mr[t] - mnew);
                lr[t] = lr[t] * scale + ls;
                float sc4[4];
                #pragma unroll
                for (int r = 0; r < 4; ++r) sc4[r] = __shfl(scale, hi * 4 + r, 64);
                #pragma unroll
                for (int n = 0; n < 8; ++n)
                    #pragma unroll
                    for (int r = 0; r < 4; ++r) oacc[t][n][r] *= sc4[r];
                mr[t] = mnew;
            } else {
                lr[t] += ls;
            }

            // ---- P -> LDS (fp16), per-wave per-subtile buffer ----
            #pragma unroll
            for (int m = 0; m < 4; ++m) {
                pk16x2 a2 = __builtin_amdgcn_cvt_pkrtz(st[t][m][0], st[t][m][1]);
                pk16x2 b2 = __builtin_amdgcn_cvt_pkrtz(st[t][m][2], st[t][m][3]);
                f16x4 w;
                w[0] = (f16)a2[0]; w[1] = (f16)a2[1]; w[2] = (f16)b2[0]; w[3] = (f16)b2[1];
                int col = (m * 16 + hi * 4) ^ swp;
                *(f16x4*)&Psh[wv][t][lo * KVBLK + col] = w;
            }
        }

        // ---- PV: O += P @ V, one vf read -> 2 MFMAs ----
        __builtin_amdgcn_s_setprio(1);
        #pragma unroll
        for (int kc2 = 0; kc2 < 2; ++kc2) {
            f16x8 pf0 = *(const f16x8*)&Psh[wv][0][lo * KVBLK + ((kc2 * 32 + hi * 8) ^ swp)];
            f16x8 pf1 = *(const f16x8*)&Psh[wv][1][lo * KVBLK + ((kc2 * 32 + hi * 8) ^ swp)];
            #pragma unroll
            for (int n = 0; n < 8; ++n) {
                int d = n * 16 + lo;
                int g = (d & 7) ^ ((d >> 3) & 7);
                f16x8 vf = *(const f16x8*)&Vsh[d * KVBLK + ((kc2 * 32 + hi * 8) ^ (g << 3))];
                oacc[0][n] = __builtin_amdgcn_mfma_f32_16x16x32_f16(pf0, vf, oacc[0][n], 0, 0, 0);
                oacc[1][n] = __builtin_amdgcn_mfma_f32_16x16x32_f16(pf1, vf, oacc[1][n], 0, 0, 0);
            }
        }
        __builtin_amdgcn_s_setprio(0);

        __syncthreads();                    // all waves done reading Ksh/Vsh
        if (kt + 1 < NKV) {
            STAGE_WRITE();                  // overwrite with next tile
            __syncthreads();                // next tile visible to all
        }
    }

    // ---- epilogue: O / l, write fp32 ----
    #pragma unroll
    for (int t = 0; t < 2; ++t) {
        float inv = 1.0f / lr[t];   // valid at lane's q = lo
        float rl[4];
        #pragma unroll
        for (int r = 0; r < 4; ++r) rl[r] = __shfl(inv, hi * 4 + r, 64);
        #pragma unroll
        for (int n = 0; n < 8; ++n)
            #pragma unroll
            for (int r = 0; r < 4; ++r)
                Oh[(wv * 32 + t * 16 + hi * 4 + r) * D_DIM + n * 16 + lo] = oacc[t][n][r] * rl[r];
    }
}

extern "C" void kernel_launch(void* const* d_in, const int* in_sizes, int n_in,
                              void* d_out, int out_size, void* d_ws, size_t ws_size,
                              hipStream_t stream) {
    const float* x2 = (const float*)d_in[0];
    const float* x3 = (const float*)d_in[1];
    float* out = (float*)d_out;
    dim3 grid(1024), block(256);
    hipLaunchKernelGGL(attn_kernel, grid, block, 0, stream, x2, x3, out);
}